// Round 2
// baseline (1730.491 us; speedup 1.0000x reference)
//
#include <hip/hip_runtime.h>
#include <math.h>

typedef __bf16 bf16;
typedef __attribute__((ext_vector_type(8))) __bf16 bf16x8;
typedef __attribute__((ext_vector_type(4))) float floatx4;

#define DIM 512
#define DFF 2048
#define SEQ 4096
#define ROWS 32768            // 8 * 4096

#define GLOBAL_AS(p) ((const __attribute__((address_space(1))) void*)(p))
#define LDS_AS(p)    ((__attribute__((address_space(3))) void*)(p))

// ---------------- weight prep: fp32 [K][N] -> bf16 [N][K] (transposed) ----------------
__global__ __launch_bounds__(256) void prep_w_kernel(const float* __restrict__ W,
                                                     bf16* __restrict__ Wt, int K, int N)
{
    int idx = blockIdx.x * 256 + threadIdx.x;
    if (idx >= K * N) return;
    int k = idx % K;
    int n = idx / K;
    Wt[idx] = (bf16)W[(size_t)k * N + n];
}

__global__ __launch_bounds__(256) void pack_bias_kernel(const float* __restrict__ bq,
                                                        const float* __restrict__ bk,
                                                        const float* __restrict__ bv,
                                                        float* __restrict__ out)
{
    int i = blockIdx.x * 256 + threadIdx.x;
    if (i >= 1536) return;
    out[i] = (i < 512) ? bq[i] : (i < 1024 ? bk[i - 512] : bv[i - 1024]);
}

// ---------------- wave reduction ----------------
__device__ inline float wave_red(float v)
{
#pragma unroll
    for (int off = 32; off; off >>= 1) v += __shfl_xor(v, off, 64);
    return v;
}

// ---------------- fused series-decomposition + LayerNorm1 ----------------
// S = x - trend (fp32 residual, lives in d_out); XN = LN(S) bf16. One wave per row.
__global__ __launch_bounds__(256) void decomp_ln_kernel(const float* __restrict__ x,
                                                        const float* __restrict__ g,
                                                        const float* __restrict__ be,
                                                        float* __restrict__ S,
                                                        bf16* __restrict__ XN)
{
    int wave = threadIdx.x >> 6, lane = threadIdx.x & 63;
    int r = blockIdx.x * 4 + wave;
    int n = r & (SEQ - 1);
    const float4* xr = (const float4*)(x + (size_t)r * DIM);
    float4 z = make_float4(0.f, 0.f, 0.f, 0.f);
    float s[8];
#pragma unroll
    for (int i = 0; i < 2; ++i) {
        int c4 = lane * 2 + i;
        float4 v0 = xr[c4];
        float4 vm = (n > 0)       ? xr[c4 - DIM / 4] : z;
        float4 vp = (n < SEQ - 1) ? xr[c4 + DIM / 4] : z;
        s[i * 4 + 0] = v0.x - (vm.x + v0.x + vp.x) * (1.f / 3.f);
        s[i * 4 + 1] = v0.y - (vm.y + v0.y + vp.y) * (1.f / 3.f);
        s[i * 4 + 2] = v0.z - (vm.z + v0.z + vp.z) * (1.f / 3.f);
        s[i * 4 + 3] = v0.w - (vm.w + v0.w + vp.w) * (1.f / 3.f);
    }
    float4* Sr = (float4*)(S + (size_t)r * DIM);
    Sr[lane * 2]     = make_float4(s[0], s[1], s[2], s[3]);
    Sr[lane * 2 + 1] = make_float4(s[4], s[5], s[6], s[7]);

    float sum = 0.f;
#pragma unroll
    for (int j = 0; j < 8; ++j) sum += s[j];
    sum = wave_red(sum);
    float mean = sum * (1.f / DIM);
    float vs = 0.f;
#pragma unroll
    for (int j = 0; j < 8; ++j) { float d = s[j] - mean; vs += d * d; }
    vs = wave_red(vs);
    float rstd = rsqrtf(vs * (1.f / DIM) + 1e-5f);

    int c = lane * 8;
    float4 g0 = ((const float4*)(g + c))[0],  g1v = ((const float4*)(g + c))[1];
    float4 b0 = ((const float4*)(be + c))[0], b1v = ((const float4*)(be + c))[1];
    bf16x8 o;
    o[0] = (bf16)((s[0] - mean) * rstd * g0.x + b0.x);
    o[1] = (bf16)((s[1] - mean) * rstd * g0.y + b0.y);
    o[2] = (bf16)((s[2] - mean) * rstd * g0.z + b0.z);
    o[3] = (bf16)((s[3] - mean) * rstd * g0.w + b0.w);
    o[4] = (bf16)((s[4] - mean) * rstd * g1v.x + b1v.x);
    o[5] = (bf16)((s[5] - mean) * rstd * g1v.y + b1v.y);
    o[6] = (bf16)((s[6] - mean) * rstd * g1v.z + b1v.z);
    o[7] = (bf16)((s[7] - mean) * rstd * g1v.w + b1v.w);
    *(bf16x8*)(XN + (size_t)r * DIM + c) = o;
}

// ---------------- plain LayerNorm (fp32 in -> bf16 out) ----------------
__global__ __launch_bounds__(256) void ln_kernel(const float* __restrict__ X,
                                                 const float* __restrict__ g,
                                                 const float* __restrict__ be,
                                                 bf16* __restrict__ XN)
{
    int wave = threadIdx.x >> 6, lane = threadIdx.x & 63;
    int r = blockIdx.x * 4 + wave;
    const float4* xr = (const float4*)(X + (size_t)r * DIM);
    float4 a0 = xr[lane * 2], a1 = xr[lane * 2 + 1];
    float s[8] = {a0.x, a0.y, a0.z, a0.w, a1.x, a1.y, a1.z, a1.w};
    float sum = 0.f;
#pragma unroll
    for (int j = 0; j < 8; ++j) sum += s[j];
    sum = wave_red(sum);
    float mean = sum * (1.f / DIM);
    float vs = 0.f;
#pragma unroll
    for (int j = 0; j < 8; ++j) { float d = s[j] - mean; vs += d * d; }
    vs = wave_red(vs);
    float rstd = rsqrtf(vs * (1.f / DIM) + 1e-5f);
    int c = lane * 8;
    float4 g0 = ((const float4*)(g + c))[0],  g1v = ((const float4*)(g + c))[1];
    float4 b0 = ((const float4*)(be + c))[0], b1v = ((const float4*)(be + c))[1];
    bf16x8 o;
    o[0] = (bf16)((s[0] - mean) * rstd * g0.x + b0.x);
    o[1] = (bf16)((s[1] - mean) * rstd * g0.y + b0.y);
    o[2] = (bf16)((s[2] - mean) * rstd * g0.z + b0.z);
    o[3] = (bf16)((s[3] - mean) * rstd * g0.w + b0.w);
    o[4] = (bf16)((s[4] - mean) * rstd * g1v.x + b1v.x);
    o[5] = (bf16)((s[5] - mean) * rstd * g1v.y + b1v.y);
    o[6] = (bf16)((s[6] - mean) * rstd * g1v.z + b1v.z);
    o[7] = (bf16)((s[7] - mean) * rstd * g1v.w + b1v.w);
    *(bf16x8*)(XN + (size_t)r * DIM + c) = o;
}

// ---------------- MFMA GEMM: C = A[M,K](bf16) @ Bt[N,K]^T(bf16) + bias, epilogues ----------------
// m97 structure: 128x128 tile, BK=32, 4 waves of 4x4 16x16x32 MFMA, global_load_lds w16.
enum { M_QKV = 0, M_ATTN = 1, M_FFN1 = 2, M_FFN2 = 3 };

template <int MODE>
__global__ __launch_bounds__(256) void gemm_bt_kernel(const bf16* __restrict__ A, int lda,
                                                      const bf16* __restrict__ Bt,
                                                      const float* __restrict__ bias,
                                                      float* S, const float* __restrict__ X,
                                                      void* Cout, int ldc,
                                                      int N, int K, int rows_per_batch,
                                                      int m_off)
{
    __shared__ __align__(16) bf16 lA[128 * 32];
    __shared__ __align__(16) bf16 lB[128 * 32];
    int tid = threadIdx.x;
    int m0 = blockIdx.y * 128;
    int n0 = blockIdx.x * 128;
    const bf16* Abase = A + (size_t)m0 * lda;
    const bf16* Bbase = Bt + (size_t)n0 * K;
    if (rows_per_batch) Bbase += (size_t)(m0 / rows_per_batch) * (size_t)N * K;

    int lane = tid & 63;
    int wave = tid >> 6;
    int wm = (wave >> 1) * 64;
    int wn = (wave & 1) * 64;
    int lm = lane & 15;
    int quad = lane >> 4;
    int i0w = tid & 192;   // wave * 64: wave-uniform staging chunk base

    floatx4 acc[4][4];
#pragma unroll
    for (int i = 0; i < 4; ++i)
#pragma unroll
        for (int j = 0; j < 4; ++j) acc[i][j] = (floatx4){0.f, 0.f, 0.f, 0.f};

    for (int k0 = 0; k0 < K; k0 += 32) {
        __syncthreads();   // previous iter's LDS reads done
#pragma unroll
        for (int it = 0; it < 2; ++it) {
            int ib = it * 256 + i0w;        // wave-uniform
            int i  = ib + lane;
            int row = i >> 2;
            int col = (i & 3) * 8;
            __builtin_amdgcn_global_load_lds(GLOBAL_AS(Abase + (size_t)row * lda + k0 + col),
                                             LDS_AS(&lA[ib * 8]), 16, 0, 0);
            __builtin_amdgcn_global_load_lds(GLOBAL_AS(Bbase + (size_t)row * K + k0 + col),
                                             LDS_AS(&lB[ib * 8]), 16, 0, 0);
        }
        __syncthreads();   // staging drained

        bf16x8 af[4], bfv[4];
#pragma unroll
        for (int i = 0; i < 4; ++i)
            af[i] = *(const bf16x8*)&lA[(wm + i * 16 + lm) * 32 + quad * 8];
#pragma unroll
        for (int j = 0; j < 4; ++j)
            bfv[j] = *(const bf16x8*)&lB[(wn + j * 16 + lm) * 32 + quad * 8];
#pragma unroll
        for (int i = 0; i < 4; ++i)
#pragma unroll
            for (int j = 0; j < 4; ++j)
                acc[i][j] = __builtin_amdgcn_mfma_f32_16x16x32_bf16(af[i], bfv[j], acc[i][j], 0, 0, 0);
    }

    // epilogue: C/D layout col = lane&15, row = quad*4 + e (m89-verified)
#pragma unroll
    for (int i = 0; i < 4; ++i) {
        int gm_base = m0 + wm + i * 16 + quad * 4;
#pragma unroll
        for (int j = 0; j < 4; ++j) {
            int gn = n0 + wn + j * 16 + lm;
            float bia = bias[gn];
#pragma unroll
            for (int e = 0; e < 4; ++e) {
                int gm = gm_base + e;
                float val = acc[i][j][e] + bia;
                if constexpr (MODE == M_QKV) {
                    if (gn < 1024) val = (val > 0.f) ? val + 1.f : __expf(val);  // elu+1 on q,k
                    ((bf16*)Cout)[(size_t)gm * ldc + gn] = (bf16)val;
                } else if constexpr (MODE == M_ATTN) {
                    S[(size_t)gm * DIM + gn] += val;          // seasonal += attn + bo
                } else if constexpr (MODE == M_FFN1) {
                    val = 0.5f * val * (1.f + erff(val * 0.70710678118654752f));  // exact gelu
                    ((bf16*)Cout)[(size_t)gm * ldc + gn] = (bf16)val;
                } else {  // M_FFN2: out = ffn2 + seasonal(out) + trend(x), fused final
                    int gmg = m_off + gm;
                    int nn = gmg & (SEQ - 1);
                    size_t o = (size_t)gmg * DIM + gn;
                    float xc = X[o];
                    float xm = (nn > 0)       ? X[o - DIM] : 0.f;
                    float xp = (nn < SEQ - 1) ? X[o + DIM] : 0.f;
                    float* op = (float*)Cout;
                    op[o] = val + op[o] + (xm + xc + xp) * (1.f / 3.f);
                }
            }
        }
    }
}

// ---------------- kv einsum partials: kv[kc][b*8+h][d][f] = sum_{n in chunk} k*v ----------------
// No atomics, no zero-init: every element written unconditionally each call.
__global__ __launch_bounds__(256) void kv_einsum_kernel(const bf16* __restrict__ QKV,
                                                        float* __restrict__ kv)
{
    int kc = blockIdx.x, h = blockIdx.y, b = blockIdx.z;
    int tid = threadIdx.x;
    __shared__ float sk[8][64];
    __shared__ float sv[8][64];
    int f = tid & 63;    // lane == f
    int dq = tid >> 6;   // wave == d-quarter
    float accv[16];
#pragma unroll
    for (int i = 0; i < 16; ++i) accv[i] = 0.f;
    const bf16* base = QKV + (size_t)(b * SEQ + kc * 512) * 1536 + h * 64;

    for (int nn = 0; nn < 512; nn += 8) {
        __syncthreads();
        {
            int e = tid * 4;                 // 256 threads * 4 = 8 rows * 128 elems
            int row = e >> 7;
            int sel = (e >> 6) & 1;          // 0 = k, 1 = v
            int col = e & 63;
            const bf16* src = base + (size_t)(nn + row) * 1536 + (sel ? 1024 : 512) + col;
            float* dst = sel ? &sv[row][col] : &sk[row][col];
#pragma unroll
            for (int t = 0; t < 4; ++t) dst[t] = (float)src[t];
        }
        __syncthreads();
#pragma unroll
        for (int r2 = 0; r2 < 8; ++r2) {
            float vv = sv[r2][f];
#pragma unroll
            for (int i = 0; i < 16; ++i)
                accv[i] += sk[r2][dq * 16 + i] * vv;
        }
    }
    float* dst = kv + (size_t)kc * 262144 + (size_t)(b * 8 + h) * 4096 + f;
#pragma unroll
    for (int i = 0; i < 16; ++i)
        dst[(dq * 16 + i) * 64] = accv[i];
}

// ---------------- fold Wo into kv (reducing 8 partials): KVWT[b][j][h*64+d] ----------------
__global__ __launch_bounds__(256) void kvw_kernel(const float* __restrict__ kv,
                                                  const float* __restrict__ Wo,
                                                  bf16* __restrict__ KVWT)
{
    int idx = blockIdx.x * 256 + threadIdx.x;   // 8*512*512
    int hd = idx & 511;
    int j  = (idx >> 9) & 511;
    int b  = idx >> 18;
    int h = hd >> 6, d = hd & 63;
    const float* kvp = kv + ((size_t)(b * 8 + h) * 64 + d) * 64;
    const float* wop = Wo + (size_t)(h * 64) * 512 + j;
    float s = 0.f;
#pragma unroll 4
    for (int f = 0; f < 64; ++f) {
        float kvv = 0.f;
#pragma unroll
        for (int c = 0; c < 8; ++c) kvv += kvp[(size_t)c * 262144 + f];
        s += kvv * wop[(size_t)f * 512];
    }
    KVWT[idx] = (bf16)s;
}

// ---------------- launch ----------------
extern "C" void kernel_launch(void* const* d_in, const int* in_sizes, int n_in,
                              void* d_out, int out_size, void* d_ws, size_t ws_size,
                              hipStream_t stream)
{
    const float* x   = (const float*)d_in[0];
    const float* Wq  = (const float*)d_in[1];
    const float* bq  = (const float*)d_in[2];
    const float* Wk  = (const float*)d_in[3];
    const float* bk  = (const float*)d_in[4];
    const float* Wv  = (const float*)d_in[5];
    const float* bv  = (const float*)d_in[6];
    const float* Wo  = (const float*)d_in[7];
    const float* bo  = (const float*)d_in[8];
    const float* g1  = (const float*)d_in[9];
    const float* b1  = (const float*)d_in[10];
    const float* g2  = (const float*)d_in[11];
    const float* b2  = (const float*)d_in[12];
    const float* Wf1 = (const float*)d_in[13];
    const float* bf1 = (const float*)d_in[14];
    const float* Wf2 = (const float*)d_in[15];
    const float* bf2 = (const float*)d_in[16];
    float* out = (float*)d_out;      // also holds seasonal residual S (fp32)
    (void)in_sizes; (void)n_in; (void)out_size; (void)ws_size;

    // workspace layout (~153 MB)
    char* ws = (char*)d_ws;
    size_t off = 0;
    auto alloc = [&](size_t bytes) -> char* {
        char* p = ws + off;
        off += (bytes + 255) & ~(size_t)255;
        return p;
    };
    bf16*  WqkvT = (bf16*)alloc((size_t)1536 * 512 * 2);    // 1.6 MB
    float* bias3 = (float*)alloc(1536 * 4);
    bf16*  Wf1T  = (bf16*)alloc((size_t)2048 * 512 * 2);    // 2.1 MB
    bf16*  Wf2T  = (bf16*)alloc((size_t)512 * 2048 * 2);    // 2.1 MB
    bf16*  XN    = (bf16*)alloc((size_t)ROWS * DIM * 2);    // 33.6 MB
    float* KV    = (float*)alloc((size_t)8 * 64 * 64 * 64 * 4);  // 8.4 MB partials
    bf16*  KVWT  = (bf16*)alloc((size_t)8 * 512 * 512 * 2); // 4.2 MB
    bf16*  QKV   = (bf16*)alloc((size_t)ROWS * 1536 * 2);   // 100.7 MB
    bf16*  H1    = QKV;   // FFN intermediate aliases QKV (dead after attn GEMM); 16384*2048*2=67MB fits

    // 1. weight prep (bf16 transpose) + bias pack
    prep_w_kernel<<<1024, 256, 0, stream>>>(Wq, WqkvT,              512, 512);
    prep_w_kernel<<<1024, 256, 0, stream>>>(Wk, WqkvT + 512 * 512,  512, 512);
    prep_w_kernel<<<1024, 256, 0, stream>>>(Wv, WqkvT + 1024 * 512, 512, 512);
    prep_w_kernel<<<4096, 256, 0, stream>>>(Wf1, Wf1T, 512, 2048);
    prep_w_kernel<<<4096, 256, 0, stream>>>(Wf2, Wf2T, 2048, 512);
    pack_bias_kernel<<<6, 256, 0, stream>>>(bq, bk, bv, bias3);

    // 2. series decomposition + LN1 (S -> d_out)
    decomp_ln_kernel<<<8192, 256, 0, stream>>>(x, g1, b1, out, XN);

    // 3. QKV projection (N=1536 GEMM; elu+1 on q,k in epilogue)
    gemm_bt_kernel<M_QKV><<<dim3(12, 256), 256, 0, stream>>>(
        XN, 512, WqkvT, bias3, nullptr, nullptr, QKV, 1536, 1536, 512, 0, 0);

    // 4. kv partials per (kc,b,h) — no atomics
    kv_einsum_kernel<<<dim3(8, 8, 8), 256, 0, stream>>>(QKV, KV);

    // 5. fold Wo, reduce partials:  KVWT[b] = (blockdiag(kv_b) @ Wo)^T bf16
    kvw_kernel<<<8192, 256, 0, stream>>>(KV, Wo, KVWT);

    // 6. attn out + residual:  out(S) += q @ KVWT_b^T + bo
    gemm_bt_kernel<M_ATTN><<<dim3(4, 256), 256, 0, stream>>>(
        QKV, 1536, KVWT, bo, out, nullptr, nullptr, 0, 512, 512, 4096, 0);

    // 7. LN2 (reads S from d_out)
    ln_kernel<<<8192, 256, 0, stream>>>(out, g2, b2, XN);

    // 8./9. FFN in 2 row-chunks (H1 aliases QKV region); FFN2 fuses +S+trend
    for (int c = 0; c < 2; ++c) {
        gemm_bt_kernel<M_FFN1><<<dim3(16, 128), 256, 0, stream>>>(
            XN + (size_t)c * 16384 * 512, 512, Wf1T, bf1, nullptr, nullptr,
            H1, 2048, 2048, 512, 0, 0);
        gemm_bt_kernel<M_FFN2><<<dim3(4, 128), 256, 0, stream>>>(
            H1, 2048, Wf2T, bf2, nullptr, x, out, 512, 512, 2048, 0, c * 16384);
    }
}

// Round 3
// 946.620 us; speedup vs baseline: 1.8281x; 1.8281x over previous
//
#include <hip/hip_runtime.h>
#include <math.h>

typedef __bf16 bf16;
typedef __attribute__((ext_vector_type(8))) __bf16 bf16x8;
typedef __attribute__((ext_vector_type(4))) float floatx4;

#define DIM 512
#define DFF 2048
#define SEQ 4096
#define ROWS 32768            // 8 * 4096

#define GLOBAL_AS(p) ((const __attribute__((address_space(1))) void*)(p))
#define LDS_AS(p)    ((__attribute__((address_space(3))) void*)(p))

// ---------------- weight prep: fp32 [K][N] -> bf16 [N][K] (transposed) ----------------
__global__ __launch_bounds__(256) void prep_w_kernel(const float* __restrict__ W,
                                                     bf16* __restrict__ Wt, int K, int N)
{
    int idx = blockIdx.x * 256 + threadIdx.x;
    if (idx >= K * N) return;
    int k = idx % K;
    int n = idx / K;
    Wt[idx] = (bf16)W[(size_t)k * N + n];
}

__global__ __launch_bounds__(256) void pack_bias_kernel(const float* __restrict__ bq,
                                                        const float* __restrict__ bk,
                                                        const float* __restrict__ bv,
                                                        float* __restrict__ out)
{
    int i = blockIdx.x * 256 + threadIdx.x;
    if (i >= 1536) return;
    out[i] = (i < 512) ? bq[i] : (i < 1024 ? bk[i - 512] : bv[i - 1024]);
}

// ---------------- wave reduction ----------------
__device__ inline float wave_red(float v)
{
#pragma unroll
    for (int off = 32; off; off >>= 1) v += __shfl_xor(v, off, 64);
    return v;
}

// ---------------- fused series-decomposition + LayerNorm1 ----------------
__global__ __launch_bounds__(256) void decomp_ln_kernel(const float* __restrict__ x,
                                                        const float* __restrict__ g,
                                                        const float* __restrict__ be,
                                                        float* __restrict__ S,
                                                        bf16* __restrict__ XN)
{
    int wave = threadIdx.x >> 6, lane = threadIdx.x & 63;
    int r = blockIdx.x * 4 + wave;
    int n = r & (SEQ - 1);
    const float4* xr = (const float4*)(x + (size_t)r * DIM);
    float4 z = make_float4(0.f, 0.f, 0.f, 0.f);
    float s[8];
#pragma unroll
    for (int i = 0; i < 2; ++i) {
        int c4 = lane * 2 + i;
        float4 v0 = xr[c4];
        float4 vm = (n > 0)       ? xr[c4 - DIM / 4] : z;
        float4 vp = (n < SEQ - 1) ? xr[c4 + DIM / 4] : z;
        s[i * 4 + 0] = v0.x - (vm.x + v0.x + vp.x) * (1.f / 3.f);
        s[i * 4 + 1] = v0.y - (vm.y + v0.y + vp.y) * (1.f / 3.f);
        s[i * 4 + 2] = v0.z - (vm.z + v0.z + vp.z) * (1.f / 3.f);
        s[i * 4 + 3] = v0.w - (vm.w + v0.w + vp.w) * (1.f / 3.f);
    }
    float4* Sr = (float4*)(S + (size_t)r * DIM);
    Sr[lane * 2]     = make_float4(s[0], s[1], s[2], s[3]);
    Sr[lane * 2 + 1] = make_float4(s[4], s[5], s[6], s[7]);

    float sum = 0.f;
#pragma unroll
    for (int j = 0; j < 8; ++j) sum += s[j];
    sum = wave_red(sum);
    float mean = sum * (1.f / DIM);
    float vs = 0.f;
#pragma unroll
    for (int j = 0; j < 8; ++j) { float d = s[j] - mean; vs += d * d; }
    vs = wave_red(vs);
    float rstd = rsqrtf(vs * (1.f / DIM) + 1e-5f);

    int c = lane * 8;
    float4 g0 = ((const float4*)(g + c))[0],  g1v = ((const float4*)(g + c))[1];
    float4 b0 = ((const float4*)(be + c))[0], b1v = ((const float4*)(be + c))[1];
    bf16x8 o;
    o[0] = (bf16)((s[0] - mean) * rstd * g0.x + b0.x);
    o[1] = (bf16)((s[1] - mean) * rstd * g0.y + b0.y);
    o[2] = (bf16)((s[2] - mean) * rstd * g0.z + b0.z);
    o[3] = (bf16)((s[3] - mean) * rstd * g0.w + b0.w);
    o[4] = (bf16)((s[4] - mean) * rstd * g1v.x + b1v.x);
    o[5] = (bf16)((s[5] - mean) * rstd * g1v.y + b1v.y);
    o[6] = (bf16)((s[6] - mean) * rstd * g1v.z + b1v.z);
    o[7] = (bf16)((s[7] - mean) * rstd * g1v.w + b1v.w);
    *(bf16x8*)(XN + (size_t)r * DIM + c) = o;
}

// ---------------- plain LayerNorm (fp32 in -> bf16 out) ----------------
__global__ __launch_bounds__(256) void ln_kernel(const float* __restrict__ X,
                                                 const float* __restrict__ g,
                                                 const float* __restrict__ be,
                                                 bf16* __restrict__ XN)
{
    int wave = threadIdx.x >> 6, lane = threadIdx.x & 63;
    int r = blockIdx.x * 4 + wave;
    const float4* xr = (const float4*)(X + (size_t)r * DIM);
    float4 a0 = xr[lane * 2], a1 = xr[lane * 2 + 1];
    float s[8] = {a0.x, a0.y, a0.z, a0.w, a1.x, a1.y, a1.z, a1.w};
    float sum = 0.f;
#pragma unroll
    for (int j = 0; j < 8; ++j) sum += s[j];
    sum = wave_red(sum);
    float mean = sum * (1.f / DIM);
    float vs = 0.f;
#pragma unroll
    for (int j = 0; j < 8; ++j) { float d = s[j] - mean; vs += d * d; }
    vs = wave_red(vs);
    float rstd = rsqrtf(vs * (1.f / DIM) + 1e-5f);
    int c = lane * 8;
    float4 g0 = ((const float4*)(g + c))[0],  g1v = ((const float4*)(g + c))[1];
    float4 b0 = ((const float4*)(be + c))[0], b1v = ((const float4*)(be + c))[1];
    bf16x8 o;
    o[0] = (bf16)((s[0] - mean) * rstd * g0.x + b0.x);
    o[1] = (bf16)((s[1] - mean) * rstd * g0.y + b0.y);
    o[2] = (bf16)((s[2] - mean) * rstd * g0.z + b0.z);
    o[3] = (bf16)((s[3] - mean) * rstd * g0.w + b0.w);
    o[4] = (bf16)((s[4] - mean) * rstd * g1v.x + b1v.x);
    o[5] = (bf16)((s[5] - mean) * rstd * g1v.y + b1v.y);
    o[6] = (bf16)((s[6] - mean) * rstd * g1v.z + b1v.z);
    o[7] = (bf16)((s[7] - mean) * rstd * g1v.w + b1v.w);
    *(bf16x8*)(XN + (size_t)r * DIM + c) = o;
}

// ---------------- MFMA GEMM: C = A[M,K](bf16) @ Bt[N,K]^T(bf16) + bias, epilogues ----------------
enum { M_QKV = 0, M_ATTN = 1, M_FFN1 = 2, M_FFN2 = 3 };

template <int MODE>
__global__ __launch_bounds__(256) void gemm_bt_kernel(const bf16* __restrict__ A, int lda,
                                                      const bf16* __restrict__ Bt,
                                                      const float* __restrict__ bias,
                                                      float* S, const float* __restrict__ X,
                                                      void* Cout, int ldc,
                                                      int N, int K, int rows_per_batch,
                                                      int m_off)
{
    __shared__ __align__(16) bf16 lA[128 * 32];
    __shared__ __align__(16) bf16 lB[128 * 32];
    int tid = threadIdx.x;
    int m0 = blockIdx.y * 128;
    int n0 = blockIdx.x * 128;
    const bf16* Abase = A + (size_t)m0 * lda;
    const bf16* Bbase = Bt + (size_t)n0 * K;
    if (rows_per_batch) Bbase += (size_t)(m0 / rows_per_batch) * (size_t)N * K;

    int lane = tid & 63;
    int wave = tid >> 6;
    int wm = (wave >> 1) * 64;
    int wn = (wave & 1) * 64;
    int lm = lane & 15;
    int quad = lane >> 4;
    int i0w = tid & 192;

    floatx4 acc[4][4];
#pragma unroll
    for (int i = 0; i < 4; ++i)
#pragma unroll
        for (int j = 0; j < 4; ++j) acc[i][j] = (floatx4){0.f, 0.f, 0.f, 0.f};

    for (int k0 = 0; k0 < K; k0 += 32) {
        __syncthreads();
#pragma unroll
        for (int it = 0; it < 2; ++it) {
            int ib = it * 256 + i0w;
            int i  = ib + lane;
            int row = i >> 2;
            int col = (i & 3) * 8;
            __builtin_amdgcn_global_load_lds(GLOBAL_AS(Abase + (size_t)row * lda + k0 + col),
                                             LDS_AS(&lA[ib * 8]), 16, 0, 0);
            __builtin_amdgcn_global_load_lds(GLOBAL_AS(Bbase + (size_t)row * K + k0 + col),
                                             LDS_AS(&lB[ib * 8]), 16, 0, 0);
        }
        __syncthreads();

        bf16x8 af[4], bfv[4];
#pragma unroll
        for (int i = 0; i < 4; ++i)
            af[i] = *(const bf16x8*)&lA[(wm + i * 16 + lm) * 32 + quad * 8];
#pragma unroll
        for (int j = 0; j < 4; ++j)
            bfv[j] = *(const bf16x8*)&lB[(wn + j * 16 + lm) * 32 + quad * 8];
#pragma unroll
        for (int i = 0; i < 4; ++i)
#pragma unroll
            for (int j = 0; j < 4; ++j)
                acc[i][j] = __builtin_amdgcn_mfma_f32_16x16x32_bf16(af[i], bfv[j], acc[i][j], 0, 0, 0);
    }

    // epilogue: C/D layout col = lane&15, row = quad*4 + e (m89-verified)
#pragma unroll
    for (int i = 0; i < 4; ++i) {
        int gm_base = m0 + wm + i * 16 + quad * 4;
#pragma unroll
        for (int j = 0; j < 4; ++j) {
            int gn = n0 + wn + j * 16 + lm;
            float bia = bias[gn];
#pragma unroll
            for (int e = 0; e < 4; ++e) {
                int gm = gm_base + e;
                float val = acc[i][j][e] + bia;
                if constexpr (MODE == M_QKV) {
                    if (gn < 1024) val = (val > 0.f) ? val + 1.f : __expf(val);  // elu+1 on q,k
                    ((bf16*)Cout)[(size_t)gm * ldc + gn] = (bf16)val;
                } else if constexpr (MODE == M_ATTN) {
                    S[(size_t)gm * DIM + gn] += val;          // seasonal += attn + bo
                } else if constexpr (MODE == M_FFN1) {
                    val = 0.5f * val * (1.f + erff(val * 0.70710678118654752f));  // exact gelu
                    ((bf16*)Cout)[(size_t)gm * ldc + gn] = (bf16)val;
                } else {  // M_FFN2: out = ffn2 + seasonal(out) + trend(x), fused final
                    int gmg = m_off + gm;
                    int nn = gmg & (SEQ - 1);
                    size_t o = (size_t)gmg * DIM + gn;
                    float xc = X[o];
                    float xm = (nn > 0)       ? X[o - DIM] : 0.f;
                    float xp = (nn < SEQ - 1) ? X[o + DIM] : 0.f;
                    float* op = (float*)Cout;
                    op[o] = val + op[o] + (xm + xc + xp) * (1.f / 3.f);
                }
            }
        }
    }
}

// ---------------- kv einsum partials: kv[kc][b*8+h][d][f] = sum_{n in chunk} k*v ----------------
__global__ __launch_bounds__(256) void kv_einsum_kernel(const bf16* __restrict__ QKV,
                                                        float* __restrict__ kv)
{
    int kc = blockIdx.x, h = blockIdx.y, b = blockIdx.z;
    int tid = threadIdx.x;
    __shared__ float sk[8][64];
    __shared__ float sv[8][64];
    int f = tid & 63;
    int dq = tid >> 6;
    float accv[16];
#pragma unroll
    for (int i = 0; i < 16; ++i) accv[i] = 0.f;
    const bf16* base = QKV + (size_t)(b * SEQ + kc * 512) * 1536 + h * 64;

    for (int nn = 0; nn < 512; nn += 8) {
        __syncthreads();
        {
            int e = tid * 4;
            int row = e >> 7;
            int sel = (e >> 6) & 1;
            int col = e & 63;
            const bf16* src = base + (size_t)(nn + row) * 1536 + (sel ? 1024 : 512) + col;
            float* dst = sel ? &sv[row][col] : &sk[row][col];
#pragma unroll
            for (int t = 0; t < 4; ++t) dst[t] = (float)src[t];
        }
        __syncthreads();
#pragma unroll
        for (int r2 = 0; r2 < 8; ++r2) {
            float vv = sv[r2][f];
#pragma unroll
            for (int i = 0; i < 16; ++i)
                accv[i] += sk[r2][dq * 16 + i] * vv;
        }
    }
    float* dst = kv + (size_t)kc * 262144 + (size_t)(b * 8 + h) * 4096 + f;
#pragma unroll
    for (int i = 0; i < 16; ++i)
        dst[(dq * 16 + i) * 64] = accv[i];
}

// ---------------- fold Wo into kv (LDS-staged, one block per (b,h)) ----------------
// KVWT[b][j][h*64+d] = sum_f (sum_c kv[c][b,h,d,f]) * Wo[h*64+f][j]
__global__ __launch_bounds__(512) void kvw_kernel(const float* __restrict__ kv,
                                                  const float* __restrict__ Wo,
                                                  bf16* __restrict__ KVWT)
{
    int bh = blockIdx.x;          // b*8 + h
    int h = bh & 7;
    int tid = threadIdx.x;        // j = 0..511
    __shared__ float skv[64][64]; // [d][f], 16 KB

    // cooperative load + partial reduction (coalesced: e contiguous across threads)
    for (int e = tid; e < 4096; e += 512) {
        float s = 0.f;
        const float* p = kv + (size_t)bh * 4096 + e;
#pragma unroll
        for (int c = 0; c < 8; ++c) s += p[(size_t)c * 262144];
        skv[e >> 6][e & 63] = s;
    }
    __syncthreads();

    float acc[64];
#pragma unroll
    for (int d = 0; d < 64; ++d) acc[d] = 0.f;
    const float* wop = Wo + (size_t)(h * 64) * 512 + tid;
#pragma unroll 4
    for (int f = 0; f < 64; ++f) {
        float w = wop[(size_t)f * 512];      // coalesced across lanes
#pragma unroll
        for (int d = 0; d < 64; ++d)
            acc[d] += skv[d][f] * w;          // wave-uniform LDS broadcast
    }

    bf16* dst = KVWT + (size_t)(bh >> 3) * 262144 + (size_t)tid * 512 + h * 64;
#pragma unroll
    for (int d8 = 0; d8 < 64; d8 += 8) {
        bf16x8 o;
#pragma unroll
        for (int t = 0; t < 8; ++t) o[t] = (bf16)acc[d8 + t];
        *(bf16x8*)(dst + d8) = o;
    }
}

// ---------------- launch ----------------
extern "C" void kernel_launch(void* const* d_in, const int* in_sizes, int n_in,
                              void* d_out, int out_size, void* d_ws, size_t ws_size,
                              hipStream_t stream)
{
    const float* x   = (const float*)d_in[0];
    const float* Wq  = (const float*)d_in[1];
    const float* bq  = (const float*)d_in[2];
    const float* Wk  = (const float*)d_in[3];
    const float* bk  = (const float*)d_in[4];
    const float* Wv  = (const float*)d_in[5];
    const float* bv  = (const float*)d_in[6];
    const float* Wo  = (const float*)d_in[7];
    const float* bo  = (const float*)d_in[8];
    const float* g1  = (const float*)d_in[9];
    const float* b1  = (const float*)d_in[10];
    const float* g2  = (const float*)d_in[11];
    const float* b2  = (const float*)d_in[12];
    const float* Wf1 = (const float*)d_in[13];
    const float* bf1 = (const float*)d_in[14];
    const float* Wf2 = (const float*)d_in[15];
    const float* bf2 = (const float*)d_in[16];
    float* out = (float*)d_out;      // also holds seasonal residual S (fp32)
    (void)in_sizes; (void)n_in; (void)out_size; (void)ws_size;

    char* ws = (char*)d_ws;
    size_t off = 0;
    auto alloc = [&](size_t bytes) -> char* {
        char* p = ws + off;
        off += (bytes + 255) & ~(size_t)255;
        return p;
    };
    bf16*  WqkvT = (bf16*)alloc((size_t)1536 * 512 * 2);
    float* bias3 = (float*)alloc(1536 * 4);
    bf16*  Wf1T  = (bf16*)alloc((size_t)2048 * 512 * 2);
    bf16*  Wf2T  = (bf16*)alloc((size_t)512 * 2048 * 2);
    bf16*  XN    = (bf16*)alloc((size_t)ROWS * DIM * 2);
    float* KV    = (float*)alloc((size_t)8 * 64 * 64 * 64 * 4);
    bf16*  KVWT  = (bf16*)alloc((size_t)8 * 512 * 512 * 2);
    bf16*  QKV   = (bf16*)alloc((size_t)ROWS * 1536 * 2);
    bf16*  H1    = QKV;   // FFN intermediate aliases QKV (dead after attn GEMM)

    prep_w_kernel<<<1024, 256, 0, stream>>>(Wq, WqkvT,              512, 512);
    prep_w_kernel<<<1024, 256, 0, stream>>>(Wk, WqkvT + 512 * 512,  512, 512);
    prep_w_kernel<<<1024, 256, 0, stream>>>(Wv, WqkvT + 1024 * 512, 512, 512);
    prep_w_kernel<<<4096, 256, 0, stream>>>(Wf1, Wf1T, 512, 2048);
    prep_w_kernel<<<4096, 256, 0, stream>>>(Wf2, Wf2T, 2048, 512);
    pack_bias_kernel<<<6, 256, 0, stream>>>(bq, bk, bv, bias3);

    decomp_ln_kernel<<<8192, 256, 0, stream>>>(x, g1, b1, out, XN);

    gemm_bt_kernel<M_QKV><<<dim3(12, 256), 256, 0, stream>>>(
        XN, 512, WqkvT, bias3, nullptr, nullptr, QKV, 1536, 1536, 512, 0, 0);

    kv_einsum_kernel<<<dim3(8, 8, 8), 256, 0, stream>>>(QKV, KV);

    kvw_kernel<<<64, 512, 0, stream>>>(KV, Wo, KVWT);

    gemm_bt_kernel<M_ATTN><<<dim3(4, 256), 256, 0, stream>>>(
        QKV, 1536, KVWT, bo, out, nullptr, nullptr, 0, 512, 512, 4096, 0);

    ln_kernel<<<8192, 256, 0, stream>>>(out, g2, b2, XN);

    for (int c = 0; c < 2; ++c) {
        gemm_bt_kernel<M_FFN1><<<dim3(16, 128), 256, 0, stream>>>(
            XN + (size_t)c * 16384 * 512, 512, Wf1T, bf1, nullptr, nullptr,
            H1, 2048, 2048, 512, 0, 0);
        gemm_bt_kernel<M_FFN2><<<dim3(4, 128), 256, 0, stream>>>(
            H1, 2048, Wf2T, bf2, nullptr, x, out, 512, 512, 2048, 0, c * 16384);
    }
}

// Round 4
// 725.043 us; speedup vs baseline: 2.3867x; 1.3056x over previous
//
#include <hip/hip_runtime.h>
#include <math.h>

typedef __bf16 bf16;
typedef __attribute__((ext_vector_type(8))) __bf16 bf16x8;
typedef __attribute__((ext_vector_type(4))) float floatx4;

#define DIM 512
#define DFF 2048
#define SEQ 4096
#define ROWS 32768            // 8 * 4096

#define GLOBAL_AS(p) ((const __attribute__((address_space(1))) void*)(p))
#define LDS_AS(p)    ((__attribute__((address_space(3))) void*)(p))

// ---------------- weight prep: fp32 [K][N] -> bf16 [N][K] (transposed) ----------------
__global__ __launch_bounds__(256) void prep_w_kernel(const float* __restrict__ W,
                                                     bf16* __restrict__ Wt, int K, int N)
{
    int idx = blockIdx.x * 256 + threadIdx.x;
    if (idx >= K * N) return;
    int k = idx % K;
    int n = idx / K;
    Wt[idx] = (bf16)W[(size_t)k * N + n];
}

__global__ __launch_bounds__(256) void pack_bias_kernel(const float* __restrict__ bq,
                                                        const float* __restrict__ bk,
                                                        const float* __restrict__ bv,
                                                        float* __restrict__ out)
{
    int i = blockIdx.x * 256 + threadIdx.x;
    if (i >= 1536) return;
    out[i] = (i < 512) ? bq[i] : (i < 1024 ? bk[i - 512] : bv[i - 1024]);
}

// ---------------- wave reduction ----------------
__device__ inline float wave_red(float v)
{
#pragma unroll
    for (int off = 32; off; off >>= 1) v += __shfl_xor(v, off, 64);
    return v;
}

// ---------------- fused series-decomposition + LayerNorm1 ----------------
__global__ __launch_bounds__(256) void decomp_ln_kernel(const float* __restrict__ x,
                                                        const float* __restrict__ g,
                                                        const float* __restrict__ be,
                                                        float* __restrict__ S,
                                                        bf16* __restrict__ XN)
{
    int wave = threadIdx.x >> 6, lane = threadIdx.x & 63;
    int r = blockIdx.x * 4 + wave;
    int n = r & (SEQ - 1);
    const float4* xr = (const float4*)(x + (size_t)r * DIM);
    float4 z = make_float4(0.f, 0.f, 0.f, 0.f);
    float s[8];
#pragma unroll
    for (int i = 0; i < 2; ++i) {
        int c4 = lane * 2 + i;
        float4 v0 = xr[c4];
        float4 vm = (n > 0)       ? xr[c4 - DIM / 4] : z;
        float4 vp = (n < SEQ - 1) ? xr[c4 + DIM / 4] : z;
        s[i * 4 + 0] = v0.x - (vm.x + v0.x + vp.x) * (1.f / 3.f);
        s[i * 4 + 1] = v0.y - (vm.y + v0.y + vp.y) * (1.f / 3.f);
        s[i * 4 + 2] = v0.z - (vm.z + v0.z + vp.z) * (1.f / 3.f);
        s[i * 4 + 3] = v0.w - (vm.w + v0.w + vp.w) * (1.f / 3.f);
    }
    float4* Sr = (float4*)(S + (size_t)r * DIM);
    Sr[lane * 2]     = make_float4(s[0], s[1], s[2], s[3]);
    Sr[lane * 2 + 1] = make_float4(s[4], s[5], s[6], s[7]);

    float sum = 0.f;
#pragma unroll
    for (int j = 0; j < 8; ++j) sum += s[j];
    sum = wave_red(sum);
    float mean = sum * (1.f / DIM);
    float vs = 0.f;
#pragma unroll
    for (int j = 0; j < 8; ++j) { float d = s[j] - mean; vs += d * d; }
    vs = wave_red(vs);
    float rstd = rsqrtf(vs * (1.f / DIM) + 1e-5f);

    int c = lane * 8;
    float4 g0 = ((const float4*)(g + c))[0],  g1v = ((const float4*)(g + c))[1];
    float4 b0 = ((const float4*)(be + c))[0], b1v = ((const float4*)(be + c))[1];
    bf16x8 o;
    o[0] = (bf16)((s[0] - mean) * rstd * g0.x + b0.x);
    o[1] = (bf16)((s[1] - mean) * rstd * g0.y + b0.y);
    o[2] = (bf16)((s[2] - mean) * rstd * g0.z + b0.z);
    o[3] = (bf16)((s[3] - mean) * rstd * g0.w + b0.w);
    o[4] = (bf16)((s[4] - mean) * rstd * g1v.x + b1v.x);
    o[5] = (bf16)((s[5] - mean) * rstd * g1v.y + b1v.y);
    o[6] = (bf16)((s[6] - mean) * rstd * g1v.z + b1v.z);
    o[7] = (bf16)((s[7] - mean) * rstd * g1v.w + b1v.w);
    *(bf16x8*)(XN + (size_t)r * DIM + c) = o;
}

// ---------------- plain LayerNorm (fp32 in -> bf16 out) ----------------
__global__ __launch_bounds__(256) void ln_kernel(const float* __restrict__ X,
                                                 const float* __restrict__ g,
                                                 const float* __restrict__ be,
                                                 bf16* __restrict__ XN)
{
    int wave = threadIdx.x >> 6, lane = threadIdx.x & 63;
    int r = blockIdx.x * 4 + wave;
    const float4* xr = (const float4*)(X + (size_t)r * DIM);
    float4 a0 = xr[lane * 2], a1 = xr[lane * 2 + 1];
    float s[8] = {a0.x, a0.y, a0.z, a0.w, a1.x, a1.y, a1.z, a1.w};
    float sum = 0.f;
#pragma unroll
    for (int j = 0; j < 8; ++j) sum += s[j];
    sum = wave_red(sum);
    float mean = sum * (1.f / DIM);
    float vs = 0.f;
#pragma unroll
    for (int j = 0; j < 8; ++j) { float d = s[j] - mean; vs += d * d; }
    vs = wave_red(vs);
    float rstd = rsqrtf(vs * (1.f / DIM) + 1e-5f);
    int c = lane * 8;
    float4 g0 = ((const float4*)(g + c))[0],  g1v = ((const float4*)(g + c))[1];
    float4 b0 = ((const float4*)(be + c))[0], b1v = ((const float4*)(be + c))[1];
    bf16x8 o;
    o[0] = (bf16)((s[0] - mean) * rstd * g0.x + b0.x);
    o[1] = (bf16)((s[1] - mean) * rstd * g0.y + b0.y);
    o[2] = (bf16)((s[2] - mean) * rstd * g0.z + b0.z);
    o[3] = (bf16)((s[3] - mean) * rstd * g0.w + b0.w);
    o[4] = (bf16)((s[4] - mean) * rstd * g1v.x + b1v.x);
    o[5] = (bf16)((s[5] - mean) * rstd * g1v.y + b1v.y);
    o[6] = (bf16)((s[6] - mean) * rstd * g1v.z + b1v.z);
    o[7] = (bf16)((s[7] - mean) * rstd * g1v.w + b1v.w);
    *(bf16x8*)(XN + (size_t)r * DIM + c) = o;
}

// ---------------- MFMA GEMM: C = A[M,K](bf16) @ Bt[N,K]^T(bf16) + bias, epilogues ----------------
enum { M_QKV = 0, M_ATTN = 1, M_FFN1 = 2, M_FFN2 = 3 };

template <int MODE>
__global__ __launch_bounds__(256) void gemm_bt_kernel(const bf16* __restrict__ A, int lda,
                                                      const bf16* __restrict__ Bt,
                                                      const float* __restrict__ bias,
                                                      float* S, const float* __restrict__ X,
                                                      void* Cout, int ldc,
                                                      int N, int K, int rows_per_batch,
                                                      int m_off)
{
    __shared__ __align__(16) bf16 lA[128 * 32];
    __shared__ __align__(16) bf16 lB[128 * 32];
    int tid = threadIdx.x;
    int m0 = blockIdx.y * 128;
    int n0 = blockIdx.x * 128;
    const bf16* Abase = A + (size_t)m0 * lda;
    const bf16* Bbase = Bt + (size_t)n0 * K;
    if (rows_per_batch) Bbase += (size_t)(m0 / rows_per_batch) * (size_t)N * K;

    int lane = tid & 63;
    int wave = tid >> 6;
    int wm = (wave >> 1) * 64;
    int wn = (wave & 1) * 64;
    int lm = lane & 15;
    int quad = lane >> 4;
    int i0w = tid & 192;

    floatx4 acc[4][4];
#pragma unroll
    for (int i = 0; i < 4; ++i)
#pragma unroll
        for (int j = 0; j < 4; ++j) acc[i][j] = (floatx4){0.f, 0.f, 0.f, 0.f};

    for (int k0 = 0; k0 < K; k0 += 32) {
        __syncthreads();
#pragma unroll
        for (int it = 0; it < 2; ++it) {
            int ib = it * 256 + i0w;
            int i  = ib + lane;
            int row = i >> 2;
            int col = (i & 3) * 8;
            __builtin_amdgcn_global_load_lds(GLOBAL_AS(Abase + (size_t)row * lda + k0 + col),
                                             LDS_AS(&lA[ib * 8]), 16, 0, 0);
            __builtin_amdgcn_global_load_lds(GLOBAL_AS(Bbase + (size_t)row * K + k0 + col),
                                             LDS_AS(&lB[ib * 8]), 16, 0, 0);
        }
        __syncthreads();

        bf16x8 af[4], bfv[4];
#pragma unroll
        for (int i = 0; i < 4; ++i)
            af[i] = *(const bf16x8*)&lA[(wm + i * 16 + lm) * 32 + quad * 8];
#pragma unroll
        for (int j = 0; j < 4; ++j)
            bfv[j] = *(const bf16x8*)&lB[(wn + j * 16 + lm) * 32 + quad * 8];
#pragma unroll
        for (int i = 0; i < 4; ++i)
#pragma unroll
            for (int j = 0; j < 4; ++j)
                acc[i][j] = __builtin_amdgcn_mfma_f32_16x16x32_bf16(af[i], bfv[j], acc[i][j], 0, 0, 0);
    }

    // epilogue: C/D layout col = lane&15, row = quad*4 + e (m89-verified)
#pragma unroll
    for (int i = 0; i < 4; ++i) {
        int gm_base = m0 + wm + i * 16 + quad * 4;
#pragma unroll
        for (int j = 0; j < 4; ++j) {
            int gn = n0 + wn + j * 16 + lm;
            float bia = bias[gn];
#pragma unroll
            for (int e = 0; e < 4; ++e) {
                int gm = gm_base + e;
                float val = acc[i][j][e] + bia;
                if constexpr (MODE == M_QKV) {
                    if (gn < 1024) val = (val > 0.f) ? val + 1.f : __expf(val);  // elu+1 on q,k
                    ((bf16*)Cout)[(size_t)gm * ldc + gn] = (bf16)val;
                } else if constexpr (MODE == M_ATTN) {
                    S[(size_t)gm * DIM + gn] += val;          // seasonal += attn + bo
                } else if constexpr (MODE == M_FFN1) {
                    val = 0.5f * val * (1.f + erff(val * 0.70710678118654752f));  // exact gelu
                    ((bf16*)Cout)[(size_t)gm * ldc + gn] = (bf16)val;
                } else {  // M_FFN2: out = ffn2 + seasonal(out) + trend(x), fused final
                    int gmg = m_off + gm;
                    int nn = gmg & (SEQ - 1);
                    size_t o = (size_t)gmg * DIM + gn;
                    float xc = X[o];
                    float xm = (nn > 0)       ? X[o - DIM] : 0.f;
                    float xp = (nn < SEQ - 1) ? X[o + DIM] : 0.f;
                    float* op = (float*)Cout;
                    op[o] = val + op[o] + (xm + xc + xp) * (1.f / 3.f);
                }
            }
        }
    }
}

// ---------------- kv einsum via MFMA: KV[kc][b*8+h][d][f] = sum_{n in kc-chunk} k[n][d]*v[n][f] ----
// One block per (kc,h,b); 4 waves split the 128-n stage into 32-n MFMA chunks.
__global__ __launch_bounds__(256) void kv_mfma_kernel(const bf16* __restrict__ QKV,
                                                      float* __restrict__ KV)
{
    int kc = blockIdx.x, h = blockIdx.y, b = blockIdx.z;
    __shared__ __align__(16) bf16 lbuf[2 * 128 * 64];   // lk | lv (natural [n][64]), 32 KB
    bf16* lk = lbuf;
    bf16* lv = lbuf + 128 * 64;
    int tid = threadIdx.x;
    int lane = tid & 63, wave = tid >> 6;
    int lm = lane & 15, quad = lane >> 4;

    floatx4 acc[4][4];
#pragma unroll
    for (int i = 0; i < 4; ++i)
#pragma unroll
        for (int j = 0; j < 4; ++j) acc[i][j] = (floatx4){0.f, 0.f, 0.f, 0.f};

    const bf16* kb = QKV + (size_t)b * SEQ * 1536 + 512 + (size_t)h * 64;
    const bf16* vb = kb + 512;
    int drow = lane >> 3;          // row-within-instruction (8 rows x 128 B = 1 KB)
    int d0 = (lane & 7) * 8;

    for (int it = 0; it < 8; ++it) {
        int n0 = kc * 1024 + it * 128;
        __syncthreads();
#pragma unroll
        for (int q = 0; q < 4; ++q) {
            int nbase = wave * 32 + q * 8;              // wave-uniform
            int ldsoff = wave * 2048 + q * 512;         // elements (x2B = bytes/2)
            __builtin_amdgcn_global_load_lds(GLOBAL_AS(kb + (size_t)(n0 + nbase + drow) * 1536 + d0),
                                             LDS_AS(&lk[ldsoff]), 16, 0, 0);
            __builtin_amdgcn_global_load_lds(GLOBAL_AS(vb + (size_t)(n0 + nbase + drow) * 1536 + d0),
                                             LDS_AS(&lv[ldsoff]), 16, 0, 0);
        }
        __syncthreads();

        int nw = wave * 32 + quad * 8;
        bf16x8 af[4], bfv[4];
#pragma unroll
        for (int i = 0; i < 4; ++i) {
            int dd = i * 16 + lm;
#pragma unroll
            for (int j = 0; j < 8; ++j) af[i][j] = lk[(nw + j) * 64 + dd];
#pragma unroll
            for (int j = 0; j < 8; ++j) bfv[i][j] = lv[(nw + j) * 64 + dd];
        }
#pragma unroll
        for (int i = 0; i < 4; ++i)
#pragma unroll
            for (int j = 0; j < 4; ++j)
                acc[i][j] = __builtin_amdgcn_mfma_f32_16x16x32_bf16(af[i], bfv[j], acc[i][j], 0, 0, 0);
    }

    // cross-wave reduce in LDS (reuse lbuf as 2 x 16 KB fp32), then store KV partial
    __syncthreads();
    float* red = (float*)lbuf;
    if (wave < 2) {
#pragma unroll
        for (int i = 0; i < 4; ++i)
#pragma unroll
            for (int j = 0; j < 4; ++j)
#pragma unroll
                for (int e = 0; e < 4; ++e)
                    red[wave * 4096 + (i * 16 + quad * 4 + e) * 64 + j * 16 + lm] = acc[i][j][e];
    }
    __syncthreads();
    if (wave >= 2) {
#pragma unroll
        for (int i = 0; i < 4; ++i)
#pragma unroll
            for (int j = 0; j < 4; ++j)
#pragma unroll
                for (int e = 0; e < 4; ++e)
                    red[(wave - 2) * 4096 + (i * 16 + quad * 4 + e) * 64 + j * 16 + lm] += acc[i][j][e];
    }
    __syncthreads();
    float* dst = KV + ((size_t)kc * 64 + b * 8 + h) * 4096;
#pragma unroll
    for (int p = 0; p < 4; ++p) {
        int e4 = (tid + p * 256) * 4;
        float4 a = *(const float4*)&red[e4];
        float4 c4 = *(const float4*)&red[4096 + e4];
        a.x += c4.x; a.y += c4.y; a.z += c4.z; a.w += c4.w;
        *(float4*)&dst[e4] = a;
    }
}

// ---------------- fold Wo (reduce 4 kc-partials): KVWT[b][j][h*64+d] ----------------
// 512 blocks = 64 (b,h) x 8 j-chunks; skv staged transposed so inner reads are b128 broadcasts.
__global__ __launch_bounds__(256) void kvw_kernel(const float* __restrict__ KV,
                                                  const float* __restrict__ Wo,
                                                  bf16* __restrict__ KVWT)
{
    int jc = blockIdx.x & 7, bh = blockIdx.x >> 3;
    int h = bh & 7, b = bh >> 3;
    __shared__ float skvT[64 * 68];   // [f][d], pad 4 keeps 16B align, 17.4 KB
    int tid = threadIdx.x;
    const float* src = KV + (size_t)bh * 4096;
#pragma unroll
    for (int p = 0; p < 16; ++p) {
        int e = tid + p * 256;
        float s = src[e] + src[e + 262144] + src[e + 524288] + src[e + 786432];
        skvT[(e & 63) * 68 + (e >> 6)] = s;     // transpose: skvT[f][d] = kv[d][f]
    }
    __syncthreads();

    int j = tid & 63, dq = tid >> 6;   // dq == wave index -> wave-uniform
    int j0 = jc * 64;
    floatx4 acc4[4];
#pragma unroll
    for (int c = 0; c < 4; ++c) acc4[c] = (floatx4){0.f, 0.f, 0.f, 0.f};
    const float* wop = Wo + (size_t)h * 64 * 512 + j0 + j;
#pragma unroll 8
    for (int f = 0; f < 64; ++f) {
        float w = wop[(size_t)f * 512];           // coalesced across lanes
        const float* sp = &skvT[f * 68 + dq * 16];
#pragma unroll
        for (int c = 0; c < 4; ++c) {
            floatx4 s = *(const floatx4*)(sp + c * 4);   // wave-uniform b128 broadcast
            acc4[c] += s * w;
        }
    }
    bf16* dst = KVWT + (size_t)b * 262144 + (size_t)(j0 + j) * 512 + h * 64 + dq * 16;
    bf16x8 o0, o1;
#pragma unroll
    for (int t = 0; t < 8; ++t) { o0[t] = (bf16)acc4[t >> 2][t & 3]; o1[t] = (bf16)acc4[2 + (t >> 2)][t & 3]; }
    *(bf16x8*)dst = o0;
    *(bf16x8*)(dst + 8) = o1;
}

// ---------------- launch ----------------
extern "C" void kernel_launch(void* const* d_in, const int* in_sizes, int n_in,
                              void* d_out, int out_size, void* d_ws, size_t ws_size,
                              hipStream_t stream)
{
    const float* x   = (const float*)d_in[0];
    const float* Wq  = (const float*)d_in[1];
    const float* bq  = (const float*)d_in[2];
    const float* Wk  = (const float*)d_in[3];
    const float* bk  = (const float*)d_in[4];
    const float* Wv  = (const float*)d_in[5];
    const float* bv  = (const float*)d_in[6];
    const float* Wo  = (const float*)d_in[7];
    const float* bo  = (const float*)d_in[8];
    const float* g1  = (const float*)d_in[9];
    const float* b1  = (const float*)d_in[10];
    const float* g2  = (const float*)d_in[11];
    const float* b2  = (const float*)d_in[12];
    const float* Wf1 = (const float*)d_in[13];
    const float* bf1 = (const float*)d_in[14];
    const float* Wf2 = (const float*)d_in[15];
    const float* bf2 = (const float*)d_in[16];
    float* out = (float*)d_out;      // also holds seasonal residual S (fp32)
    (void)in_sizes; (void)n_in; (void)out_size; (void)ws_size;

    char* ws = (char*)d_ws;
    size_t off = 0;
    auto alloc = [&](size_t bytes) -> char* {
        char* p = ws + off;
        off += (bytes + 255) & ~(size_t)255;
        return p;
    };
    bf16*  WqkvT = (bf16*)alloc((size_t)1536 * 512 * 2);
    float* bias3 = (float*)alloc(1536 * 4);
    bf16*  Wf1T  = (bf16*)alloc((size_t)2048 * 512 * 2);
    bf16*  Wf2T  = (bf16*)alloc((size_t)512 * 2048 * 2);
    bf16*  XN    = (bf16*)alloc((size_t)ROWS * DIM * 2);
    float* KV    = (float*)alloc((size_t)4 * 64 * 4096 * 4);  // 4 kc-partials
    bf16*  KVWT  = (bf16*)alloc((size_t)8 * 512 * 512 * 2);
    bf16*  QKV   = (bf16*)alloc((size_t)ROWS * 1536 * 2);
    bf16*  H1    = QKV;   // FFN intermediate aliases QKV (dead after attn GEMM)

    prep_w_kernel<<<1024, 256, 0, stream>>>(Wq, WqkvT,              512, 512);
    prep_w_kernel<<<1024, 256, 0, stream>>>(Wk, WqkvT + 512 * 512,  512, 512);
    prep_w_kernel<<<1024, 256, 0, stream>>>(Wv, WqkvT + 1024 * 512, 512, 512);
    prep_w_kernel<<<4096, 256, 0, stream>>>(Wf1, Wf1T, 512, 2048);
    prep_w_kernel<<<4096, 256, 0, stream>>>(Wf2, Wf2T, 2048, 512);
    pack_bias_kernel<<<6, 256, 0, stream>>>(bq, bk, bv, bias3);

    decomp_ln_kernel<<<8192, 256, 0, stream>>>(x, g1, b1, out, XN);

    gemm_bt_kernel<M_QKV><<<dim3(12, 256), 256, 0, stream>>>(
        XN, 512, WqkvT, bias3, nullptr, nullptr, QKV, 1536, 1536, 512, 0, 0);

    kv_mfma_kernel<<<dim3(4, 8, 8), 256, 0, stream>>>(QKV, KV);

    kvw_kernel<<<512, 256, 0, stream>>>(KV, Wo, KVWT);

    gemm_bt_kernel<M_ATTN><<<dim3(4, 256), 256, 0, stream>>>(
        QKV, 1536, KVWT, bo, out, nullptr, nullptr, 0, 512, 512, 4096, 0);

    ln_kernel<<<8192, 256, 0, stream>>>(out, g2, b2, XN);

    for (int c = 0; c < 2; ++c) {
        gemm_bt_kernel<M_FFN1><<<dim3(16, 128), 256, 0, stream>>>(
            XN + (size_t)c * 16384 * 512, 512, Wf1T, bf1, nullptr, nullptr,
            H1, 2048, 2048, 512, 0, 0);
        gemm_bt_kernel<M_FFN2><<<dim3(4, 128), 256, 0, stream>>>(
            H1, 2048, Wf2T, bf2, nullptr, x, out, 512, 512, 2048, 0, c * 16384);
    }
}